// Round 1
// baseline (244.851 us; speedup 1.0000x reference)
//
#include <hip/hip_runtime.h>

// Problem constants (match reference file)
constexpr int N_EMB = 8192;
constexpr int D_EMB = 512;     // 512 floats = 128 float4 per row
constexpr int T_TRI = 262144;
#define MARGIN_F 1.0f

// ---------------------------------------------------------------------------
// Kernel 1: per-row inverse L2 norm. One wave per row (4 rows / 256-thr block).
// Each lane reads 8 floats (2x float4), shuffle-reduce sum of squares.
// Block 0 also zeroes the global accumulator.
// ---------------------------------------------------------------------------
__global__ __launch_bounds__(256) void norms_kernel(const float* __restrict__ emb,
                                                    float* __restrict__ inv_norm,
                                                    float* __restrict__ acc) {
    if (blockIdx.x == 0 && threadIdx.x == 0) acc[0] = 0.0f;
    const int lane = threadIdx.x & 63;
    const int row  = (blockIdx.x << 2) + (threadIdx.x >> 6);
    const float4* p = (const float4*)(emb + (size_t)row * D_EMB);
    float4 v0 = p[lane];
    float4 v1 = p[lane + 64];
    float s = v0.x * v0.x + v0.y * v0.y + v0.z * v0.z + v0.w * v0.w
            + v1.x * v1.x + v1.y * v1.y + v1.z * v1.z + v1.w * v1.w;
#pragma unroll
    for (int off = 32; off > 0; off >>= 1) s += __shfl_down(s, off, 64);
    if (lane == 0) inv_norm[row] = rsqrtf(s);
}

// ---------------------------------------------------------------------------
// Kernel 2: triplet loss accumulation. One wave per triplet (grid-stride).
// loss_t = relu((sn*inv_n - sp*inv_p)*inv_a + margin)
// where sp = <a,p>, sn = <a,n> over raw (unnormalized) rows.
// ---------------------------------------------------------------------------
__global__ __launch_bounds__(256) void triplet_kernel(const float* __restrict__ emb,
                                                      const float* __restrict__ inv_norm,
                                                      const int* __restrict__ ind_a,
                                                      const int* __restrict__ ind_p,
                                                      const int* __restrict__ ind_n,
                                                      float* __restrict__ acc) {
    const int lane    = threadIdx.x & 63;
    const int waveIb  = threadIdx.x >> 6;            // wave within block (0..3)
    const int waveId  = (blockIdx.x << 2) + waveIb;  // global wave id
    const int nWaves  = gridDim.x << 2;

    float local = 0.0f;
    for (int t = waveId; t < T_TRI; t += nWaves) {
        const int a = ind_a[t];
        const int p = ind_p[t];
        const int n = ind_n[t];
        const float4* pa = (const float4*)(emb + (size_t)a * D_EMB);
        const float4* pp = (const float4*)(emb + (size_t)p * D_EMB);
        const float4* pn = (const float4*)(emb + (size_t)n * D_EMB);
        float4 a0 = pa[lane], a1 = pa[lane + 64];
        float4 p0 = pp[lane], p1 = pp[lane + 64];
        float4 n0 = pn[lane], n1 = pn[lane + 64];

        float sp = a0.x * p0.x + a0.y * p0.y + a0.z * p0.z + a0.w * p0.w
                 + a1.x * p1.x + a1.y * p1.y + a1.z * p1.z + a1.w * p1.w;
        float sn = a0.x * n0.x + a0.y * n0.y + a0.z * n0.z + a0.w * n0.w
                 + a1.x * n1.x + a1.y * n1.y + a1.z * n1.z + a1.w * n1.w;
#pragma unroll
        for (int off = 32; off > 0; off >>= 1) {
            sp += __shfl_down(sp, off, 64);
            sn += __shfl_down(sn, off, 64);
        }
        if (lane == 0) {
            float v = (sn * inv_norm[n] - sp * inv_norm[p]) * inv_norm[a] + MARGIN_F;
            local += fmaxf(v, 0.0f);
        }
    }

    __shared__ float smem[4];
    if (lane == 0) smem[waveIb] = local;
    __syncthreads();
    if (threadIdx.x == 0) {
        atomicAdd(acc, smem[0] + smem[1] + smem[2] + smem[3]);
    }
}

// ---------------------------------------------------------------------------
// Kernel 3: finalize mean.
// ---------------------------------------------------------------------------
__global__ void finalize_kernel(const float* __restrict__ acc, float* __restrict__ out) {
    out[0] = acc[0] * (1.0f / (float)T_TRI);
}

extern "C" void kernel_launch(void* const* d_in, const int* in_sizes, int n_in,
                              void* d_out, int out_size, void* d_ws, size_t ws_size,
                              hipStream_t stream) {
    const float* emb   = (const float*)d_in[0];
    const int*   ind_a = (const int*)d_in[1];
    const int*   ind_p = (const int*)d_in[2];
    const int*   ind_n = (const int*)d_in[3];
    float* out = (float*)d_out;

    // Workspace layout: inv_norm[N_EMB] floats, then 1 float accumulator.
    float* inv_norm = (float*)d_ws;
    float* acc      = inv_norm + N_EMB;

    norms_kernel<<<N_EMB / 4, 256, 0, stream>>>(emb, inv_norm, acc);

    // 8192 blocks x 4 waves = 32768 waves; 8 triplets per wave.
    triplet_kernel<<<8192, 256, 0, stream>>>(emb, inv_norm, ind_a, ind_p, ind_n, acc);

    finalize_kernel<<<1, 1, 0, stream>>>(acc, out);
}

// Round 2
// 199.049 us; speedup vs baseline: 1.2301x; 1.2301x over previous
//
#include <hip/hip_runtime.h>

// Problem constants (match reference file)
constexpr int N_EMB = 8192;
constexpr int D_EMB = 512;     // 512 floats per row
constexpr int T_TRI = 262144;
#define MARGIN_F 1.0f

// bf16 table: 8192 rows x 512 bf16 = 8 MB in workspace.
constexpr size_t TAB_BYTES = (size_t)N_EMB * D_EMB * 2;

__device__ __forceinline__ unsigned bf16_rne(float f) {
    unsigned x = __float_as_uint(f);
    return (x + 0x7fffu + ((x >> 16) & 1u)) >> 16;
}

// ---------------------------------------------------------------------------
// Kernel 1: normalize each row, store as bf16 (RNE) into ws table.
// One wave per row (4 rows / 256-thr block); lane holds 8 floats (2x float4).
// Butterfly reduce so all lanes get the norm. Block 0 zeroes the accumulator.
// ---------------------------------------------------------------------------
__global__ __launch_bounds__(256) void prep_kernel(const float* __restrict__ emb,
                                                   unsigned short* __restrict__ tab,
                                                   float* __restrict__ acc) {
    if (blockIdx.x == 0 && threadIdx.x == 0) acc[0] = 0.0f;
    const int lane = threadIdx.x & 63;
    const int row  = (blockIdx.x << 2) + (threadIdx.x >> 6);
    const float4* p = (const float4*)(emb + (size_t)row * D_EMB);
    float4 v0 = p[lane];
    float4 v1 = p[lane + 64];
    float s = v0.x * v0.x + v0.y * v0.y + v0.z * v0.z + v0.w * v0.w
            + v1.x * v1.x + v1.y * v1.y + v1.z * v1.z + v1.w * v1.w;
#pragma unroll
    for (int off = 32; off > 0; off >>= 1) s += __shfl_xor(s, off, 64);
    const float inv = rsqrtf(s);

    v0.x *= inv; v0.y *= inv; v0.z *= inv; v0.w *= inv;
    v1.x *= inv; v1.y *= inv; v1.z *= inv; v1.w *= inv;

    // v0 covers elements [4*lane, +4); v1 covers [4*lane+256, +4).
    uint2 o0, o1;
    o0.x = bf16_rne(v0.x) | (bf16_rne(v0.y) << 16);
    o0.y = bf16_rne(v0.z) | (bf16_rne(v0.w) << 16);
    o1.x = bf16_rne(v1.x) | (bf16_rne(v1.y) << 16);
    o1.y = bf16_rne(v1.z) | (bf16_rne(v1.w) << 16);

    char* rowb = (char*)(tab + (size_t)row * D_EMB);
    *(uint2*)(rowb + 8 * lane)       = o0;
    *(uint2*)(rowb + 8 * lane + 512) = o1;
}

// Unpack-and-accumulate: dot of 8 bf16 pairs held in two uint4s.
__device__ __forceinline__ float bdot8(uint4 a, uint4 b) {
    float s = 0.0f;
    const unsigned aw[4] = {a.x, a.y, a.z, a.w};
    const unsigned bw[4] = {b.x, b.y, b.z, b.w};
#pragma unroll
    for (int i = 0; i < 4; ++i) {
        float alo = __uint_as_float(aw[i] << 16);
        float ahi = __uint_as_float(aw[i] & 0xffff0000u);
        float blo = __uint_as_float(bw[i] << 16);
        float bhi = __uint_as_float(bw[i] & 0xffff0000u);
        s = fmaf(alo, blo, s);
        s = fmaf(ahi, bhi, s);
    }
    return s;
}

// ---------------------------------------------------------------------------
// Kernel 2: one wave per triplet, grid-stride, 2 triplets in flight per iter.
// Row = 1 KB bf16; lane reads one uint4 (16 B = 8 bf16) per row.
// loss_t = relu(<a,n> - <a,p> + margin) on normalized rows.
// ---------------------------------------------------------------------------
__global__ __launch_bounds__(256) void triplet_kernel(const unsigned short* __restrict__ tab,
                                                      const int* __restrict__ ind_a,
                                                      const int* __restrict__ ind_p,
                                                      const int* __restrict__ ind_n,
                                                      float* __restrict__ acc) {
    const int lane   = threadIdx.x & 63;
    const int waveIb = threadIdx.x >> 6;
    const int waveId = (blockIdx.x << 2) + waveIb;
    const int nWaves = gridDim.x << 2;

    float local = 0.0f;
    for (int t = waveId; t < T_TRI; t += 2 * nWaves) {
        const int t1 = t + nWaves;
        const bool has1 = (t1 < T_TRI);

        const int a0 = ind_a[t];
        const int p0 = ind_p[t];
        const int n0 = ind_n[t];
        const int a1 = has1 ? ind_a[t1] : a0;
        const int p1 = has1 ? ind_p[t1] : p0;
        const int n1 = has1 ? ind_n[t1] : n0;

        const uint4* ra0 = (const uint4*)(tab + (size_t)a0 * D_EMB);
        const uint4* rp0 = (const uint4*)(tab + (size_t)p0 * D_EMB);
        const uint4* rn0 = (const uint4*)(tab + (size_t)n0 * D_EMB);
        const uint4* ra1 = (const uint4*)(tab + (size_t)a1 * D_EMB);
        const uint4* rp1 = (const uint4*)(tab + (size_t)p1 * D_EMB);
        const uint4* rn1 = (const uint4*)(tab + (size_t)n1 * D_EMB);

        uint4 va0 = ra0[lane], vp0 = rp0[lane], vn0 = rn0[lane];
        uint4 va1 = ra1[lane], vp1 = rp1[lane], vn1 = rn1[lane];

        float sp0 = bdot8(va0, vp0);
        float sn0 = bdot8(va0, vn0);
        float sp1 = bdot8(va1, vp1);
        float sn1 = bdot8(va1, vn1);

#pragma unroll
        for (int off = 32; off > 0; off >>= 1) {
            sp0 += __shfl_down(sp0, off, 64);
            sn0 += __shfl_down(sn0, off, 64);
            sp1 += __shfl_down(sp1, off, 64);
            sn1 += __shfl_down(sn1, off, 64);
        }
        if (lane == 0) {
            local += fmaxf(sn0 - sp0 + MARGIN_F, 0.0f);
            if (has1) local += fmaxf(sn1 - sp1 + MARGIN_F, 0.0f);
        }
    }

    __shared__ float smem[4];
    if (lane == 0) smem[waveIb] = local;
    __syncthreads();
    if (threadIdx.x == 0) {
        atomicAdd(acc, smem[0] + smem[1] + smem[2] + smem[3]);
    }
}

// ---------------------------------------------------------------------------
// Kernel 3: finalize mean.
// ---------------------------------------------------------------------------
__global__ void finalize_kernel(const float* __restrict__ acc, float* __restrict__ out) {
    out[0] = acc[0] * (1.0f / (float)T_TRI);
}

extern "C" void kernel_launch(void* const* d_in, const int* in_sizes, int n_in,
                              void* d_out, int out_size, void* d_ws, size_t ws_size,
                              hipStream_t stream) {
    const float* emb   = (const float*)d_in[0];
    const int*   ind_a = (const int*)d_in[1];
    const int*   ind_p = (const int*)d_in[2];
    const int*   ind_n = (const int*)d_in[3];
    float* out = (float*)d_out;

    // Workspace layout: bf16 table (8 MB), then 1 float accumulator.
    unsigned short* tab = (unsigned short*)d_ws;
    float* acc = (float*)((char*)d_ws + TAB_BYTES);

    prep_kernel<<<N_EMB / 4, 256, 0, stream>>>(emb, tab, acc);

    // 8192 blocks x 4 waves = 32768 waves; 8 triplets per wave (2 in flight).
    triplet_kernel<<<8192, 256, 0, stream>>>(tab, ind_a, ind_p, ind_n, acc);

    finalize_kernel<<<1, 1, 0, stream>>>(acc, out);
}